// Round 1
// baseline (21632.587 us; speedup 1.0000x reference)
//
#include <hip/hip_runtime.h>

#define FIN   128
#define HEADS 4
#define HID   32
#define NCLS  40
#define NEG_SLOPE 0.2f

// ---- float atomic-max via order-preserving uint key ----
__device__ inline unsigned fkey(float f) {
    unsigned u = __float_as_uint(f);
    return (u & 0x80000000u) ? ~u : (u | 0x80000000u);
}
__device__ inline float funkey(unsigned k) {
    return (k & 0x80000000u) ? __uint_as_float(k & 0x7fffffffu)
                             : __uint_as_float(~k);
}

// ---- GEMM: Y[n,NO] = X[n,K] @ W[K,NO], one thread per output elem ----
template<int K>
__global__ void gemm_k(const float* __restrict__ X, const float* __restrict__ W,
                       float* __restrict__ Y, int n, int NO) {
    int idx = blockIdx.x * blockDim.x + threadIdx.x;
    long total = (long)n * NO;
    if (idx >= total) return;
    int row = idx / NO, col = idx % NO;
    const float* x = X + (size_t)row * K;
    float acc = 0.f;
#pragma unroll
    for (int k = 0; k < K; ++k) acc += x[k] * W[k * NO + col];
    Y[idx] = acc;
}

// ---- attention logits: s_src[n,h] = <h[n,h,:], a_src[h,:]>, same for dst ----
__global__ void scores_k(const float* __restrict__ H, const float* __restrict__ asrc,
                         const float* __restrict__ adst, float* __restrict__ ssrc,
                         float* __restrict__ sdst, int n, int heads, int ch) {
    int idx = blockIdx.x * blockDim.x + threadIdx.x;
    if (idx >= n * heads) return;
    int node = idx / heads, h = idx % heads;
    const float* hp = H + (size_t)node * heads * ch + h * ch;
    const float* as = asrc + h * ch;
    const float* ad = adst + h * ch;
    float a = 0.f, b = 0.f;
    for (int c = 0; c < ch; ++c) { float v = hp[c]; a += v * as[c]; b += v * ad[c]; }
    ssrc[idx] = a;
    sdst[idx] = b;
}

// ---- per-edge segment max ----
__global__ void edge_max_k(const int* __restrict__ ei, int E, int Etot,
                           const float* __restrict__ ssrc, const float* __restrict__ sdst,
                           unsigned* __restrict__ emaxk, int heads) {
    int e = blockIdx.x * blockDim.x + threadIdx.x;
    if (e >= Etot) return;
    int s, d;
    if (e < E) { s = ei[e]; d = ei[E + e]; } else { s = d = e - E; }
    for (int h = 0; h < heads; ++h) {
        float v = ssrc[s * heads + h] + sdst[d * heads + h];
        v = (v >= 0.f) ? v : NEG_SLOPE * v;
        atomicMax(&emaxk[d * heads + h], fkey(v));
    }
}

// ---- per-edge exp + segment sum ----
__global__ void edge_exp_k(const int* __restrict__ ei, int E, int Etot,
                           const float* __restrict__ ssrc, const float* __restrict__ sdst,
                           const unsigned* __restrict__ emaxk, float* __restrict__ ex,
                           float* __restrict__ denom, int heads) {
    int e = blockIdx.x * blockDim.x + threadIdx.x;
    if (e >= Etot) return;
    int s, d;
    if (e < E) { s = ei[e]; d = ei[E + e]; } else { s = d = e - E; }
    for (int h = 0; h < heads; ++h) {
        float v = ssrc[s * heads + h] + sdst[d * heads + h];
        v = (v >= 0.f) ? v : NEG_SLOPE * v;
        float m = funkey(emaxk[d * heads + h]);
        float xv = __expf(v - m);
        ex[(size_t)e * heads + h] = xv;
        atomicAdd(&denom[d * heads + h], xv);
    }
}

// ---- per-(edge,head) weighted aggregation ----
__global__ void edge_aggr_k(const int* __restrict__ ei, int E, int Etot,
                            const float* __restrict__ Hf, const float* __restrict__ ex,
                            const float* __restrict__ denom, float* __restrict__ out,
                            int heads, int ch) {
    int idx = blockIdx.x * blockDim.x + threadIdx.x;
    long total = (long)Etot * heads;
    if (idx >= total) return;
    int e = idx / heads, h = idx % heads;
    int s, d;
    if (e < E) { s = ei[e]; d = ei[E + e]; } else { s = d = e - E; }
    float alpha = ex[idx] / (denom[d * heads + h] + 1e-16f);
    const float* hp = Hf + (size_t)s * heads * ch + h * ch;
    float* op = out + (size_t)d * heads * ch + h * ch;
    for (int c = 0; c < ch; c += 4) {
        float4 v = *reinterpret_cast<const float4*>(hp + c);
        atomicAdd(&op[c + 0], v.x * alpha);
        atomicAdd(&op[c + 1], v.y * alpha);
        atomicAdd(&op[c + 2], v.z * alpha);
        atomicAdd(&op[c + 3], v.w * alpha);
    }
}

// ---- bias + ELU (layers 0/1) ----
__global__ void bias_elu_k(float* __restrict__ Y, const float* __restrict__ b, int n, int NO) {
    int idx = blockIdx.x * blockDim.x + threadIdx.x;
    if (idx >= n * NO) return;
    float v = Y[idx] + b[idx % NO];
    Y[idx] = (v > 0.f) ? v : expm1f(v);
}

// ---- bias + log_softmax over 40 classes (layer 2) ----
__global__ void logsoftmax_k(const float* __restrict__ L, const float* __restrict__ b2,
                             float* __restrict__ out, int n) {
    int node = blockIdx.x * blockDim.x + threadIdx.x;
    if (node >= n) return;
    float vals[NCLS];
    float m = -1e30f;
    for (int c = 0; c < NCLS; ++c) {
        float v = L[(size_t)node * NCLS + c] + b2[c];
        vals[c] = v;
        m = fmaxf(m, v);
    }
    float ssum = 0.f;
    for (int c = 0; c < NCLS; ++c) ssum += __expf(vals[c] - m);
    float lse = m + logf(ssum);
    for (int c = 0; c < NCLS; ++c) out[(size_t)node * NCLS + c] = vals[c] - lse;
}

static inline dim3 g1(long t) { return dim3((unsigned)((t + 255) / 256)); }

extern "C" void kernel_launch(void* const* d_in, const int* in_sizes, int n_in,
                              void* d_out, int out_size, void* d_ws, size_t ws_size,
                              hipStream_t stream) {
    const float* x      = (const float*)d_in[0];
    const int*   ei     = (const int*)d_in[1];
    const float* W0     = (const float*)d_in[2];
    const float* a_src0 = (const float*)d_in[3];
    const float* a_dst0 = (const float*)d_in[4];
    const float* b0     = (const float*)d_in[5];
    const float* W1     = (const float*)d_in[6];
    const float* a_src1 = (const float*)d_in[7];
    const float* a_dst1 = (const float*)d_in[8];
    const float* b1     = (const float*)d_in[9];
    const float* W2     = (const float*)d_in[10];
    const float* a_src2 = (const float*)d_in[11];
    const float* a_dst2 = (const float*)d_in[12];
    const float* b2     = (const float*)d_in[13];

    const int N    = in_sizes[0] / FIN;
    const int E    = in_sizes[1] / 2;
    const int Etot = E + N;

    float* ws = (float*)d_ws;
    size_t o = 0;
    float*    hA    = ws + o; o += (size_t)N * FIN;
    float*    hB    = ws + o; o += (size_t)N * FIN;
    float*    ssrc  = ws + o; o += (size_t)N * HEADS;
    float*    sdst  = ws + o; o += (size_t)N * HEADS;
    unsigned* emaxk = (unsigned*)(ws + o); o += (size_t)N * HEADS;
    float*    denom = ws + o; o += (size_t)N * HEADS;
    float*    ex    = ws + o; o += (size_t)Etot * HEADS;

    // ---------------- Layer 0: x[N,128] -> hB[N,128] ----------------
    gemm_k<FIN><<<g1((long)N * 128), 256, 0, stream>>>(x, W0, hA, N, 128);
    scores_k<<<g1((long)N * HEADS), 256, 0, stream>>>(hA, a_src0, a_dst0, ssrc, sdst, N, HEADS, HID);
    hipMemsetAsync(emaxk, 0, (size_t)N * HEADS * 4, stream);
    hipMemsetAsync(denom, 0, (size_t)N * HEADS * 4, stream);
    hipMemsetAsync(hB, 0, (size_t)N * FIN * 4, stream);
    edge_max_k<<<g1(Etot), 256, 0, stream>>>(ei, E, Etot, ssrc, sdst, emaxk, HEADS);
    edge_exp_k<<<g1(Etot), 256, 0, stream>>>(ei, E, Etot, ssrc, sdst, emaxk, ex, denom, HEADS);
    edge_aggr_k<<<g1((long)Etot * HEADS), 256, 0, stream>>>(ei, E, Etot, hA, ex, denom, hB, HEADS, HID);
    bias_elu_k<<<g1((long)N * 128), 256, 0, stream>>>(hB, b0, N, 128);

    // ---------------- Layer 1: hB[N,128] -> hB[N,128] ----------------
    gemm_k<FIN><<<g1((long)N * 128), 256, 0, stream>>>(hB, W1, hA, N, 128);
    scores_k<<<g1((long)N * HEADS), 256, 0, stream>>>(hA, a_src1, a_dst1, ssrc, sdst, N, HEADS, HID);
    hipMemsetAsync(emaxk, 0, (size_t)N * HEADS * 4, stream);
    hipMemsetAsync(denom, 0, (size_t)N * HEADS * 4, stream);
    hipMemsetAsync(hB, 0, (size_t)N * FIN * 4, stream);
    edge_max_k<<<g1(Etot), 256, 0, stream>>>(ei, E, Etot, ssrc, sdst, emaxk, HEADS);
    edge_exp_k<<<g1(Etot), 256, 0, stream>>>(ei, E, Etot, ssrc, sdst, emaxk, ex, denom, HEADS);
    edge_aggr_k<<<g1((long)Etot * HEADS), 256, 0, stream>>>(ei, E, Etot, hA, ex, denom, hB, HEADS, HID);
    bias_elu_k<<<g1((long)N * 128), 256, 0, stream>>>(hB, b1, N, 128);

    // ---------------- Layer 2: hB[N,128] -> logits[N,40] -> log_softmax ----------------
    gemm_k<FIN><<<g1((long)N * NCLS), 256, 0, stream>>>(hB, W2, hA, N, NCLS);
    scores_k<<<g1((long)N * 1), 256, 0, stream>>>(hA, a_src2, a_dst2, ssrc, sdst, N, 1, NCLS);
    hipMemsetAsync(emaxk, 0, (size_t)N * 4, stream);
    hipMemsetAsync(denom, 0, (size_t)N * 4, stream);
    hipMemsetAsync(hB, 0, (size_t)N * NCLS * 4, stream);
    edge_max_k<<<g1(Etot), 256, 0, stream>>>(ei, E, Etot, ssrc, sdst, emaxk, 1);
    edge_exp_k<<<g1(Etot), 256, 0, stream>>>(ei, E, Etot, ssrc, sdst, emaxk, ex, denom, 1);
    edge_aggr_k<<<g1((long)Etot * 1), 256, 0, stream>>>(ei, E, Etot, hA, ex, denom, hB, 1, NCLS);
    logsoftmax_k<<<g1(N), 256, 0, stream>>>(hB, b2, (float*)d_out, N);
}

// Round 2
// 1188.550 us; speedup vs baseline: 18.2008x; 18.2008x over previous
//
#include <hip/hip_runtime.h>

#define FIN   128
#define HEADS 4
#define HID   32
#define NCLS  40
#define NEG_SLOPE 0.2f

// ================= GEMM: Y[n,NO] = X[n,K] @ W[K,NO], 4 cols/thread =========
template<int K>
__global__ void gemm4_k(const float* __restrict__ X, const float* __restrict__ W,
                        float* __restrict__ Y, int n, int NO) {
    int idx = blockIdx.x * blockDim.x + threadIdx.x;
    int ng = NO >> 2;                       // NO divisible by 4 (128, 40)
    long total = (long)n * ng;
    if (idx >= total) return;
    int row = idx / ng, cg = idx % ng;
    const float* x = X + (size_t)row * K;
    const float* w = W + cg * 4;
    float4 acc = {0.f, 0.f, 0.f, 0.f};
#pragma unroll
    for (int k = 0; k < K; ++k) {
        float xv = x[k];
        float4 wv = *reinterpret_cast<const float4*>(w + (size_t)k * NO);
        acc.x += xv * wv.x; acc.y += xv * wv.y;
        acc.z += xv * wv.z; acc.w += xv * wv.w;
    }
    *reinterpret_cast<float4*>(Y + (size_t)row * NO + cg * 4) = acc;
}

// ================= attention logits per node ================================
__global__ void scores_k(const float* __restrict__ H, const float* __restrict__ asrc,
                         const float* __restrict__ adst, float* __restrict__ ssrc,
                         float* __restrict__ sdst, int n, int heads, int ch) {
    int idx = blockIdx.x * blockDim.x + threadIdx.x;
    if (idx >= n * heads) return;
    int node = idx / heads, h = idx % heads;
    const float* hp = H + (size_t)node * heads * ch + h * ch;
    const float* as = asrc + h * ch;
    const float* ad = adst + h * ch;
    float a = 0.f, b = 0.f;
    for (int c = 0; c < ch; ++c) { float v = hp[c]; a += v * as[c]; b += v * ad[c]; }
    ssrc[idx] = a;
    sdst[idx] = b;
}

// ================= CSR build ================================================
__global__ void hist_k(const int* __restrict__ ei, int E, int Etot, int* __restrict__ cnt) {
    int e = blockIdx.x * blockDim.x + threadIdx.x;
    if (e >= Etot) return;
    int d = (e < E) ? ei[E + e] : e - E;
    atomicAdd(&cnt[d], 1);
}

__global__ void scan1_k(const int* __restrict__ cnt, int* __restrict__ excl,
                        int* __restrict__ bsum, int n) {
    __shared__ int tmp[256];
    int i = blockIdx.x * 256 + threadIdx.x;
    int v = (i < n) ? cnt[i] : 0;
    tmp[threadIdx.x] = v;
    __syncthreads();
    for (int off = 1; off < 256; off <<= 1) {
        int t = (threadIdx.x >= off) ? tmp[threadIdx.x - off] : 0;
        __syncthreads();
        tmp[threadIdx.x] += t;
        __syncthreads();
    }
    if (i < n) excl[i] = tmp[threadIdx.x] - v;
    if (threadIdx.x == 255) bsum[blockIdx.x] = tmp[255];
}

__global__ void scan2_k(int* __restrict__ bsum, int nb) {
    __shared__ int tmp[512];
    int i = threadIdx.x;
    int v = (i < nb) ? bsum[i] : 0;
    tmp[i] = v;
    __syncthreads();
    for (int off = 1; off < 512; off <<= 1) {
        int t = (i >= off) ? tmp[i - off] : 0;
        __syncthreads();
        tmp[i] += t;
        __syncthreads();
    }
    if (i < nb) bsum[i] = tmp[i] - v;   // exclusive
}

__global__ void scan3_k(const int* __restrict__ excl, const int* __restrict__ bsum,
                        int* __restrict__ rowptr, int* __restrict__ cursor,
                        int n, int total) {
    int i = blockIdx.x * 256 + threadIdx.x;
    if (i < n) {
        int r = excl[i] + bsum[blockIdx.x];
        rowptr[i] = r;
        cursor[i] = r;
    }
    if (i == 0) rowptr[n] = total;
}

__global__ void scatter_k(const int* __restrict__ ei, int E, int Etot,
                          int* __restrict__ cursor, int* __restrict__ cols) {
    int e = blockIdx.x * blockDim.x + threadIdx.x;
    if (e >= Etot) return;
    int s, d;
    if (e < E) { s = ei[e]; d = ei[E + e]; } else { s = d = e - E; }
    int pos = atomicAdd(&cursor[d], 1);
    cols[pos] = s;
}

// ================= fused per-node softmax + aggregation =====================
// one wave (64 threads) per destination node; no atomics
template<int HH, int CH>
__global__ void gat_node_k(const int* __restrict__ rp, const int* __restrict__ cols,
                           const float* __restrict__ H, const float* __restrict__ ssrc,
                           const float* __restrict__ sdst, const float* __restrict__ bias,
                           float* __restrict__ out, int n, int elu) {
    constexpr int F = HH * CH;
    int d = blockIdx.x;
    if (d >= n) return;
    int lane = threadIdx.x;
    int beg = rp[d], end = rp[d + 1];
    int deg = end - beg;

    float sd[HH];
#pragma unroll
    for (int h = 0; h < HH; ++h) sd[h] = sdst[d * HH + h];

    // ---- phase 1a: per-head max over incoming edges ----
    float m[HH];
#pragma unroll
    for (int h = 0; h < HH; ++h) m[h] = -1e30f;
    for (int i = lane; i < deg; i += 64) {
        int s = cols[beg + i];
        float sv[HH];
        if constexpr (HH == 4) {
            float4 t = *reinterpret_cast<const float4*>(ssrc + (size_t)s * 4);
            sv[0] = t.x; sv[1] = t.y; sv[2] = t.z; sv[3] = t.w;
        } else {
            sv[0] = ssrc[s];
        }
#pragma unroll
        for (int h = 0; h < HH; ++h) {
            float v = sv[h] + sd[h];
            v = (v >= 0.f) ? v : NEG_SLOPE * v;
            m[h] = fmaxf(m[h], v);
        }
    }
#pragma unroll
    for (int h = 0; h < HH; ++h)
        for (int off = 32; off > 0; off >>= 1)
            m[h] = fmaxf(m[h], __shfl_xor(m[h], off, 64));

    // ---- phase 1b: softmax denominator ----
    float den[HH];
#pragma unroll
    for (int h = 0; h < HH; ++h) den[h] = 0.f;
    for (int i = lane; i < deg; i += 64) {
        int s = cols[beg + i];
        float sv[HH];
        if constexpr (HH == 4) {
            float4 t = *reinterpret_cast<const float4*>(ssrc + (size_t)s * 4);
            sv[0] = t.x; sv[1] = t.y; sv[2] = t.z; sv[3] = t.w;
        } else {
            sv[0] = ssrc[s];
        }
#pragma unroll
        for (int h = 0; h < HH; ++h) {
            float v = sv[h] + sd[h];
            v = (v >= 0.f) ? v : NEG_SLOPE * v;
            den[h] += __expf(v - m[h]);
        }
    }
#pragma unroll
    for (int h = 0; h < HH; ++h) {
        for (int off = 32; off > 0; off >>= 1)
            den[h] += __shfl_xor(den[h], off, 64);
        den[h] = 1.f / (den[h] + 1e-16f);
    }

    // ---- phase 2: chunked weighted aggregation ----
    __shared__ float alpha_s[64 * HH];
    __shared__ int   src_s[64];
    float acc0 = 0.f, acc1 = 0.f;

    for (int cbase = 0; cbase < deg; cbase += 64) {
        int cnt = min(64, deg - cbase);
        if (lane < cnt) {
            int s = cols[beg + cbase + lane];
            src_s[lane] = s;
            float sv[HH];
            if constexpr (HH == 4) {
                float4 t = *reinterpret_cast<const float4*>(ssrc + (size_t)s * 4);
                sv[0] = t.x; sv[1] = t.y; sv[2] = t.z; sv[3] = t.w;
            } else {
                sv[0] = ssrc[s];
            }
#pragma unroll
            for (int h = 0; h < HH; ++h) {
                float v = sv[h] + sd[h];
                v = (v >= 0.f) ? v : NEG_SLOPE * v;
                alpha_s[lane * HH + h] = __expf(v - m[h]) * den[h];
            }
        }
        __syncthreads();
        for (int e = 0; e < cnt; ++e) {
            int s = src_s[e];
            const float* hp = H + (size_t)s * F;
            if constexpr (F > 64) {
                float a0 = alpha_s[e * HH + (lane / CH)];
                float a1 = alpha_s[e * HH + ((lane + 64) / CH)];
                acc0 += a0 * hp[lane];
                acc1 += a1 * hp[lane + 64];
            } else {
                if (lane < F) acc0 += alpha_s[e * HH + (lane / CH)] * hp[lane];
            }
        }
        __syncthreads();
    }

    // ---- epilogue: bias (+ELU) ----
    if constexpr (F > 64) {
        float v0 = acc0 + bias[lane];
        float v1 = acc1 + bias[lane + 64];
        if (elu) {
            v0 = (v0 > 0.f) ? v0 : expm1f(v0);
            v1 = (v1 > 0.f) ? v1 : expm1f(v1);
        }
        out[(size_t)d * F + lane]      = v0;
        out[(size_t)d * F + lane + 64] = v1;
    } else {
        if (lane < F) {
            float v0 = acc0 + bias[lane];
            if (elu) v0 = (v0 > 0.f) ? v0 : expm1f(v0);
            out[(size_t)d * F + lane] = v0;
        }
    }
}

// ================= bias + log_softmax (layer 2 epilogue) ====================
__global__ void logsoftmax_k(const float* __restrict__ L, float* __restrict__ out, int n) {
    int node = blockIdx.x * blockDim.x + threadIdx.x;
    if (node >= n) return;
    float vals[NCLS];
    float m = -1e30f;
    for (int c = 0; c < NCLS; ++c) {
        float v = L[(size_t)node * NCLS + c];
        vals[c] = v;
        m = fmaxf(m, v);
    }
    float ssum = 0.f;
    for (int c = 0; c < NCLS; ++c) ssum += __expf(vals[c] - m);
    float lse = m + logf(ssum);
    for (int c = 0; c < NCLS; ++c) out[(size_t)node * NCLS + c] = vals[c] - lse;
}

static inline dim3 g1(long t) { return dim3((unsigned)((t + 255) / 256)); }

extern "C" void kernel_launch(void* const* d_in, const int* in_sizes, int n_in,
                              void* d_out, int out_size, void* d_ws, size_t ws_size,
                              hipStream_t stream) {
    const float* x      = (const float*)d_in[0];
    const int*   ei     = (const int*)d_in[1];
    const float* W0     = (const float*)d_in[2];
    const float* a_src0 = (const float*)d_in[3];
    const float* a_dst0 = (const float*)d_in[4];
    const float* b0     = (const float*)d_in[5];
    const float* W1     = (const float*)d_in[6];
    const float* a_src1 = (const float*)d_in[7];
    const float* a_dst1 = (const float*)d_in[8];
    const float* b1     = (const float*)d_in[9];
    const float* W2     = (const float*)d_in[10];
    const float* a_src2 = (const float*)d_in[11];
    const float* a_dst2 = (const float*)d_in[12];
    const float* b2     = (const float*)d_in[13];

    const int N    = in_sizes[0] / FIN;
    const int E    = in_sizes[1] / 2;
    const int Etot = E + N;

    float* ws = (float*)d_ws;
    size_t o = 0;
    float* hA   = ws + o; o += (size_t)N * FIN;
    float* hB   = ws + o; o += (size_t)N * FIN;
    float* ssrc = ws + o; o += (size_t)N * HEADS;
    float* sdst = ws + o; o += (size_t)N * HEADS;
    int* cnt    = (int*)(ws + o); o += N;
    int* excl   = (int*)(ws + o); o += N;
    int* bsum   = (int*)(ws + o); o += 512;
    int* rowptr = (int*)(ws + o); o += N + 1;
    int* cursor = (int*)(ws + o); o += N;
    int* cols   = (int*)(ws + o); o += Etot;

    const int nScanBlocks = (N + 255) / 256;

    // ---------------- CSR by destination (once; shared by all 3 layers) -----
    hipMemsetAsync(cnt, 0, (size_t)N * 4, stream);
    hist_k<<<g1(Etot), 256, 0, stream>>>(ei, E, Etot, cnt);
    scan1_k<<<nScanBlocks, 256, 0, stream>>>(cnt, excl, bsum, N);
    scan2_k<<<1, 512, 0, stream>>>(bsum, nScanBlocks);
    scan3_k<<<nScanBlocks, 256, 0, stream>>>(excl, bsum, rowptr, cursor, N, Etot);
    scatter_k<<<g1(Etot), 256, 0, stream>>>(ei, E, Etot, cursor, cols);

    // ---------------- Layer 0: x[N,128] -> hB[N,128] ------------------------
    gemm4_k<FIN><<<g1((long)N * 32), 256, 0, stream>>>(x, W0, hA, N, 128);
    scores_k<<<g1((long)N * HEADS), 256, 0, stream>>>(hA, a_src0, a_dst0, ssrc, sdst, N, HEADS, HID);
    gat_node_k<HEADS, HID><<<N, 64, 0, stream>>>(rowptr, cols, hA, ssrc, sdst, b0, hB, N, 1);

    // ---------------- Layer 1: hB[N,128] -> hB[N,128] -----------------------
    gemm4_k<FIN><<<g1((long)N * 32), 256, 0, stream>>>(hB, W1, hA, N, 128);
    scores_k<<<g1((long)N * HEADS), 256, 0, stream>>>(hA, a_src1, a_dst1, ssrc, sdst, N, HEADS, HID);
    gat_node_k<HEADS, HID><<<N, 64, 0, stream>>>(rowptr, cols, hA, ssrc, sdst, b1, hB, N, 1);

    // ---------------- Layer 2: hB[N,128] -> logits[N,40] -> log_softmax -----
    gemm4_k<FIN><<<g1((long)N * 10), 256, 0, stream>>>(hB, W2, hA, N, NCLS);
    scores_k<<<g1((long)N * 1), 256, 0, stream>>>(hA, a_src2, a_dst2, ssrc, sdst, N, 1, NCLS);
    gat_node_k<1, NCLS><<<N, 64, 0, stream>>>(rowptr, cols, hA, ssrc, sdst, b2, hB, N, 0);
    logsoftmax_k<<<g1(N), 256, 0, stream>>>(hB, (float*)d_out, N);
}

// Round 3
// 629.332 us; speedup vs baseline: 34.3739x; 1.8886x over previous
//
#include <hip/hip_runtime.h>
#include <hip/hip_bf16.h>

#define FIN   128
#define HEADS 4
#define HID   32
#define NCLS  40
#define NEG_SLOPE 0.2f

typedef __bf16 bf16x8 __attribute__((ext_vector_type(8)));
typedef float  f32x4  __attribute__((ext_vector_type(4)));

__device__ inline unsigned short bf16_rne(float f) {
    unsigned u = __float_as_uint(f);
    return (unsigned short)((u + 0x7fffu + ((u >> 16) & 1u)) >> 16);
}
__device__ inline float bf16_to_f(unsigned short h) {
    return __uint_as_float(((unsigned)h) << 16);
}

// ===== pack W[k,col] fp32 -> B-fragment-ordered bf16 hi/lo planes ===========
// layout: element ((t*NC + c)*64 + lane)*8 + i  holds  B[k = t*32 + (lane>>4)*8 + i][col = c*16 + (lane&15)]
template<int NC>
__global__ void packW_k(const float* __restrict__ W, unsigned short* __restrict__ Bhi,
                        unsigned short* __restrict__ Blo, int NO) {
    int idx = blockIdx.x * 256 + threadIdx.x;
    int total = 4 * NC * 64 * 8;
    if (idx >= total) return;
    int i = idx & 7;
    int rest = idx >> 3;
    int l = rest & 63;
    int rest2 = rest >> 6;
    int c = rest2 % NC;
    int t = rest2 / NC;
    int k   = t * 32 + (l >> 4) * 8 + i;
    int col = c * 16 + (l & 15);
    float val = (col < NO) ? W[(size_t)k * NO + col] : 0.f;
    unsigned short hi = bf16_rne(val);
    unsigned short lo = bf16_rne(val - bf16_to_f(hi));
    Bhi[idx] = hi;
    Blo[idx] = lo;
}

// ===== MFMA GEMM: Y[n,NO] = X[n,128] @ W[128,NO], split-bf16 ================
// wave handles 32 rows x NO cols; block = 4 waves = 128 rows
template<int NC>
__global__ __launch_bounds__(256) void gemm_mfma_k(
        const float* __restrict__ X, const unsigned short* __restrict__ Bhi,
        const unsigned short* __restrict__ Blo, float* __restrict__ Y,
        int n, int NO) {
    int wave = threadIdx.x >> 6;
    int lane = threadIdx.x & 63;
    int rowbase = (blockIdx.x * 4 + wave) * 32;
    if (rowbase >= n) return;
    int r0 = lane & 15, kg = lane >> 4;

    f32x4 acc[2][NC];
#pragma unroll
    for (int rt = 0; rt < 2; ++rt)
#pragma unroll
        for (int c = 0; c < NC; ++c) acc[rt][c] = f32x4{0.f, 0.f, 0.f, 0.f};

    for (int t = 0; t < 4; ++t) {
        // --- A fragments (hi/lo) for both row sub-tiles, converted on the fly
        union U { unsigned short u[8]; bf16x8 v; };
        U ah[2], al[2];
#pragma unroll
        for (int rt = 0; rt < 2; ++rt) {
            int row = min(rowbase + rt * 16 + r0, n - 1);
            const float* xp = X + (size_t)row * 128 + t * 32 + kg * 8;
            float4 xa = *reinterpret_cast<const float4*>(xp);
            float4 xb = *reinterpret_cast<const float4*>(xp + 4);
            float f[8] = {xa.x, xa.y, xa.z, xa.w, xb.x, xb.y, xb.z, xb.w};
#pragma unroll
            for (int i = 0; i < 8; ++i) {
                unsigned short h = bf16_rne(f[i]);
                ah[rt].u[i] = h;
                al[rt].u[i] = bf16_rne(f[i] - bf16_to_f(h));
            }
        }
        // --- per col-tile: load B hi/lo frags, 3 MFMAs per row sub-tile
#pragma unroll
        for (int c = 0; c < NC; ++c) {
            size_t boff = (((size_t)t * NC + c) * 64 + lane) * 8;
            bf16x8 bh = *reinterpret_cast<const bf16x8*>(Bhi + boff);
            bf16x8 bl = *reinterpret_cast<const bf16x8*>(Blo + boff);
#pragma unroll
            for (int rt = 0; rt < 2; ++rt) {
                acc[rt][c] = __builtin_amdgcn_mfma_f32_16x16x32_bf16(ah[rt].v, bh, acc[rt][c], 0, 0, 0);
                acc[rt][c] = __builtin_amdgcn_mfma_f32_16x16x32_bf16(al[rt].v, bh, acc[rt][c], 0, 0, 0);
                acc[rt][c] = __builtin_amdgcn_mfma_f32_16x16x32_bf16(ah[rt].v, bl, acc[rt][c], 0, 0, 0);
            }
        }
    }

    // --- store: C layout col = lane&15, row = (lane>>4)*4 + reg
#pragma unroll
    for (int rt = 0; rt < 2; ++rt)
#pragma unroll
        for (int c = 0; c < NC; ++c)
#pragma unroll
            for (int r = 0; r < 4; ++r) {
                int row = rowbase + rt * 16 + kg * 4 + r;
                int col = c * 16 + r0;
                if (row < n && col < NO)
                    Y[(size_t)row * NO + col] = acc[rt][c][r];
            }
}

// ===== attention logits per node (float4) ===================================
__global__ void scores_k(const float* __restrict__ H, const float* __restrict__ asrc,
                         const float* __restrict__ adst, float* __restrict__ ssrc,
                         float* __restrict__ sdst, int n, int heads, int ch) {
    int idx = blockIdx.x * blockDim.x + threadIdx.x;
    if (idx >= n * heads) return;
    int node = idx / heads, h = idx % heads;
    const float4* hp = reinterpret_cast<const float4*>(H + (size_t)node * heads * ch + h * ch);
    const float4* as = reinterpret_cast<const float4*>(asrc + h * ch);
    const float4* ad = reinterpret_cast<const float4*>(adst + h * ch);
    float a = 0.f, b = 0.f;
    for (int c = 0; c < ch / 4; ++c) {
        float4 v = hp[c], s = as[c], d = ad[c];
        a += v.x * s.x + v.y * s.y + v.z * s.z + v.w * s.w;
        b += v.x * d.x + v.y * d.y + v.z * d.z + v.w * d.w;
    }
    ssrc[idx] = a;
    sdst[idx] = b;
}

// ===== CSR build ============================================================
__global__ void hist_k(const int* __restrict__ ei, int E, int Etot, int* __restrict__ cnt) {
    int e = blockIdx.x * blockDim.x + threadIdx.x;
    if (e >= Etot) return;
    int d = (e < E) ? ei[E + e] : e - E;
    atomicAdd(&cnt[d], 1);
}

__global__ void scan1_k(const int* __restrict__ cnt, int* __restrict__ excl,
                        int* __restrict__ bsum, int n) {
    __shared__ int tmp[256];
    int i = blockIdx.x * 256 + threadIdx.x;
    int v = (i < n) ? cnt[i] : 0;
    tmp[threadIdx.x] = v;
    __syncthreads();
    for (int off = 1; off < 256; off <<= 1) {
        int t = (threadIdx.x >= off) ? tmp[threadIdx.x - off] : 0;
        __syncthreads();
        tmp[threadIdx.x] += t;
        __syncthreads();
    }
    if (i < n) excl[i] = tmp[threadIdx.x] - v;
    if (threadIdx.x == 255) bsum[blockIdx.x] = tmp[255];
}

__global__ void scan2_k(int* __restrict__ bsum, int nb) {
    __shared__ int tmp[512];
    int i = threadIdx.x;
    int v = (i < nb) ? bsum[i] : 0;
    tmp[i] = v;
    __syncthreads();
    for (int off = 1; off < 512; off <<= 1) {
        int t = (i >= off) ? tmp[i - off] : 0;
        __syncthreads();
        tmp[i] += t;
        __syncthreads();
    }
    if (i < nb) bsum[i] = tmp[i] - v;   // exclusive
}

__global__ void scan3_k(const int* __restrict__ excl, const int* __restrict__ bsum,
                        int* __restrict__ rowptr, int* __restrict__ cursor,
                        int n, int total) {
    int i = blockIdx.x * 256 + threadIdx.x;
    if (i < n) {
        int r = excl[i] + bsum[blockIdx.x];
        rowptr[i] = r;
        cursor[i] = r;
    }
    if (i == 0) rowptr[n] = total;
}

__global__ void scatter_k(const int* __restrict__ ei, int E, int Etot,
                          int* __restrict__ cursor, int* __restrict__ cols) {
    int e = blockIdx.x * blockDim.x + threadIdx.x;
    if (e >= Etot) return;
    int s, d;
    if (e < E) { s = ei[e]; d = ei[E + e]; } else { s = d = e - E; }
    int pos = atomicAdd(&cursor[d], 1);
    cols[pos] = s;
}

// ===== fused per-node online-softmax + aggregation (one wave / node) ========
template<int HH, int CH>
__global__ void gat_node_k(const int* __restrict__ rp, const int* __restrict__ cols,
                           const float* __restrict__ H, const float* __restrict__ ssrc,
                           const float* __restrict__ sdst, const float* __restrict__ bias,
                           float* __restrict__ out, int n, int elu) {
    constexpr int F = HH * CH;
    int d = blockIdx.x;
    if (d >= n) return;
    int lane = threadIdx.x;
    int beg = rp[d], end = rp[d + 1];
    int deg = end - beg;

    float sd[HH];
#pragma unroll
    for (int h = 0; h < HH; ++h) sd[h] = sdst[d * HH + h];

    // ---- phase 1: online max + denom in one pass ----
    float m[HH], den[HH];
#pragma unroll
    for (int h = 0; h < HH; ++h) { m[h] = -1e30f; den[h] = 0.f; }
    for (int i = lane; i < deg; i += 64) {
        int s = cols[beg + i];
        float sv[HH];
        if constexpr (HH == 4) {
            float4 t = *reinterpret_cast<const float4*>(ssrc + (size_t)s * 4);
            sv[0] = t.x; sv[1] = t.y; sv[2] = t.z; sv[3] = t.w;
        } else {
            sv[0] = ssrc[s];
        }
#pragma unroll
        for (int h = 0; h < HH; ++h) {
            float v = sv[h] + sd[h];
            v = (v >= 0.f) ? v : NEG_SLOPE * v;
            float nm = fmaxf(m[h], v);
            den[h] = den[h] * __expf(m[h] - nm) + __expf(v - nm);
            m[h] = nm;
        }
    }
#pragma unroll
    for (int h = 0; h < HH; ++h) {
        for (int off = 32; off > 0; off >>= 1) {
            float om = __shfl_xor(m[h], off, 64);
            float od = __shfl_xor(den[h], off, 64);
            float nm = fmaxf(m[h], om);
            den[h] = den[h] * __expf(m[h] - nm) + od * __expf(om - nm);
            m[h] = nm;
        }
        den[h] = 1.f / (den[h] + 1e-16f);
    }

    // ---- phase 2: chunked weighted aggregation ----
    __shared__ float alpha_s[64 * HH];
    __shared__ int   src_s[64];
    float acc0 = 0.f, acc1 = 0.f;

    for (int cbase = 0; cbase < deg; cbase += 64) {
        int cnt = min(64, deg - cbase);
        if (lane < cnt) {
            int s = cols[beg + cbase + lane];
            src_s[lane] = s;
            float sv[HH];
            if constexpr (HH == 4) {
                float4 t = *reinterpret_cast<const float4*>(ssrc + (size_t)s * 4);
                sv[0] = t.x; sv[1] = t.y; sv[2] = t.z; sv[3] = t.w;
            } else {
                sv[0] = ssrc[s];
            }
#pragma unroll
            for (int h = 0; h < HH; ++h) {
                float v = sv[h] + sd[h];
                v = (v >= 0.f) ? v : NEG_SLOPE * v;
                alpha_s[lane * HH + h] = __expf(v - m[h]) * den[h];
            }
        }
        __syncthreads();
        for (int e = 0; e < cnt; ++e) {
            int s = src_s[e];
            const float* hp = H + (size_t)s * F;
            if constexpr (F > 64) {
                float a0 = alpha_s[e * HH + (lane / CH)];
                float a1 = alpha_s[e * HH + ((lane + 64) / CH)];
                acc0 += a0 * hp[lane];
                acc1 += a1 * hp[lane + 64];
            } else {
                if (lane < F) acc0 += alpha_s[e * HH + (lane / CH)] * hp[lane];
            }
        }
        __syncthreads();
    }

    // ---- epilogue: bias (+ELU) ----
    if constexpr (F > 64) {
        float v0 = acc0 + bias[lane];
        float v1 = acc1 + bias[lane + 64];
        if (elu) {
            v0 = (v0 > 0.f) ? v0 : expm1f(v0);
            v1 = (v1 > 0.f) ? v1 : expm1f(v1);
        }
        out[(size_t)d * F + lane]      = v0;
        out[(size_t)d * F + lane + 64] = v1;
    } else {
        if (lane < F) {
            float v0 = acc0 + bias[lane];
            if (elu) v0 = (v0 > 0.f) ? v0 : expm1f(v0);
            out[(size_t)d * F + lane] = v0;
        }
    }
}

// ===== bias + log_softmax (layer 2 epilogue) ================================
__global__ void logsoftmax_k(const float* __restrict__ L, float* __restrict__ out, int n) {
    int node = blockIdx.x * blockDim.x + threadIdx.x;
    if (node >= n) return;
    float vals[NCLS];
    float m = -1e30f;
    for (int c = 0; c < NCLS; ++c) {
        float v = L[(size_t)node * NCLS + c];
        vals[c] = v;
        m = fmaxf(m, v);
    }
    float ssum = 0.f;
    for (int c = 0; c < NCLS; ++c) ssum += __expf(vals[c] - m);
    float lse = m + logf(ssum);
    for (int c = 0; c < NCLS; ++c) out[(size_t)node * NCLS + c] = vals[c] - lse;
}

static inline dim3 g1(long t) { return dim3((unsigned)((t + 255) / 256)); }

extern "C" void kernel_launch(void* const* d_in, const int* in_sizes, int n_in,
                              void* d_out, int out_size, void* d_ws, size_t ws_size,
                              hipStream_t stream) {
    const float* x      = (const float*)d_in[0];
    const int*   ei     = (const int*)d_in[1];
    const float* W0     = (const float*)d_in[2];
    const float* a_src0 = (const float*)d_in[3];
    const float* a_dst0 = (const float*)d_in[4];
    const float* b0     = (const float*)d_in[5];
    const float* W1     = (const float*)d_in[6];
    const float* a_src1 = (const float*)d_in[7];
    const float* a_dst1 = (const float*)d_in[8];
    const float* b1     = (const float*)d_in[9];
    const float* W2     = (const float*)d_in[10];
    const float* a_src2 = (const float*)d_in[11];
    const float* a_dst2 = (const float*)d_in[12];
    const float* b2     = (const float*)d_in[13];

    const int N    = in_sizes[0] / FIN;
    const int E    = in_sizes[1] / 2;
    const int Etot = E + N;

    float* ws = (float*)d_ws;
    size_t o = 0;
    float* hA   = ws + o; o += (size_t)N * FIN;
    float* hB   = ws + o; o += (size_t)N * FIN;
    float* ssrc = ws + o; o += (size_t)N * HEADS;
    float* sdst = ws + o; o += (size_t)N * HEADS;
    int* cnt    = (int*)(ws + o); o += N;
    int* excl   = (int*)(ws + o); o += N;
    int* bsum   = (int*)(ws + o); o += 512;
    int* rowptr = (int*)(ws + o); o += N + 1;
    int* cursor = (int*)(ws + o); o += N;
    int* cols   = (int*)(ws + o); o += Etot;
    unsigned short* Bhi0 = (unsigned short*)(ws + o); o += 4 * 8 * 64 * 8 / 2;
    unsigned short* Blo0 = (unsigned short*)(ws + o); o += 4 * 8 * 64 * 8 / 2;
    unsigned short* Bhi1 = (unsigned short*)(ws + o); o += 4 * 8 * 64 * 8 / 2;
    unsigned short* Blo1 = (unsigned short*)(ws + o); o += 4 * 8 * 64 * 8 / 2;
    unsigned short* Bhi2 = (unsigned short*)(ws + o); o += 4 * 3 * 64 * 8 / 2;
    unsigned short* Blo2 = (unsigned short*)(ws + o); o += 4 * 3 * 64 * 8 / 2;

    const int nScanBlocks = (N + 255) / 256;
    const int gemmBlocks  = (N + 127) / 128;

    // ---------------- CSR by destination + weight packing (shared) ----------
    hipMemsetAsync(cnt, 0, (size_t)N * 4, stream);
    hist_k<<<g1(Etot), 256, 0, stream>>>(ei, E, Etot, cnt);
    packW_k<8><<<g1(4 * 8 * 64 * 8), 256, 0, stream>>>(W0, Bhi0, Blo0, 128);
    packW_k<8><<<g1(4 * 8 * 64 * 8), 256, 0, stream>>>(W1, Bhi1, Blo1, 128);
    packW_k<3><<<g1(4 * 3 * 64 * 8), 256, 0, stream>>>(W2, Bhi2, Blo2, NCLS);
    scan1_k<<<nScanBlocks, 256, 0, stream>>>(cnt, excl, bsum, N);
    scan2_k<<<1, 512, 0, stream>>>(bsum, nScanBlocks);
    scan3_k<<<nScanBlocks, 256, 0, stream>>>(excl, bsum, rowptr, cursor, N, Etot);
    scatter_k<<<g1(Etot), 256, 0, stream>>>(ei, E, Etot, cursor, cols);

    // ---------------- Layer 0 ----------------------------------------------
    gemm_mfma_k<8><<<gemmBlocks, 256, 0, stream>>>(x, Bhi0, Blo0, hA, N, 128);
    scores_k<<<g1((long)N * HEADS), 256, 0, stream>>>(hA, a_src0, a_dst0, ssrc, sdst, N, HEADS, HID);
    gat_node_k<HEADS, HID><<<N, 64, 0, stream>>>(rowptr, cols, hA, ssrc, sdst, b0, hB, N, 1);

    // ---------------- Layer 1 ----------------------------------------------
    gemm_mfma_k<8><<<gemmBlocks, 256, 0, stream>>>(hB, Bhi1, Blo1, hA, N, 128);
    scores_k<<<g1((long)N * HEADS), 256, 0, stream>>>(hA, a_src1, a_dst1, ssrc, sdst, N, HEADS, HID);
    gat_node_k<HEADS, HID><<<N, 64, 0, stream>>>(rowptr, cols, hA, ssrc, sdst, b1, hB, N, 1);

    // ---------------- Layer 2 ----------------------------------------------
    gemm_mfma_k<3><<<gemmBlocks, 256, 0, stream>>>(hB, Bhi2, Blo2, hA, N, NCLS);
    scores_k<<<g1((long)N * 1), 256, 0, stream>>>(hA, a_src2, a_dst2, ssrc, sdst, N, 1, NCLS);
    gat_node_k<1, NCLS><<<N, 64, 0, stream>>>(rowptr, cols, hA, ssrc, sdst, b2, hB, N, 0);
    logsoftmax_k<<<g1(N), 256, 0, stream>>>(hB, (float*)d_out, N);
}

// Round 4
// 581.540 us; speedup vs baseline: 37.1988x; 1.0822x over previous
//
#include <hip/hip_runtime.h>
#include <hip/hip_bf16.h>

#define FIN   128
#define HEADS 4
#define HID   32
#define NCLS  40
#define NEG_SLOPE 0.2f

typedef __bf16 bf16x8 __attribute__((ext_vector_type(8)));
typedef float  f32x4  __attribute__((ext_vector_type(4)));

__device__ inline unsigned short bf16_rne(float f) {
    unsigned u = __float_as_uint(f);
    return (unsigned short)((u + 0x7fffu + ((u >> 16) & 1u)) >> 16);
}
__device__ inline float bf16_to_f(unsigned short h) {
    return __uint_as_float(((unsigned)h) << 16);
}

// ===== pack W[k,col] fp32 -> B-fragment-ordered bf16 hi/lo planes ===========
template<int NC>
__global__ void packW_k(const float* __restrict__ W, unsigned short* __restrict__ Bhi,
                        unsigned short* __restrict__ Blo, int NO) {
    int idx = blockIdx.x * 256 + threadIdx.x;
    int total = 4 * NC * 64 * 8;
    if (idx >= total) return;
    int i = idx & 7;
    int rest = idx >> 3;
    int l = rest & 63;
    int rest2 = rest >> 6;
    int c = rest2 % NC;
    int t = rest2 / NC;
    int k   = t * 32 + (l >> 4) * 8 + i;
    int col = c * 16 + (l & 15);
    float val = (col < NO) ? W[(size_t)k * NO + col] : 0.f;
    unsigned short hi = bf16_rne(val);
    unsigned short lo = bf16_rne(val - bf16_to_f(hi));
    Bhi[idx] = hi;
    Blo[idx] = lo;
}

// ===== MFMA GEMM: Y[n,NO] = X[n,128] @ W[128,NO], split-bf16 ================
template<int NC>
__global__ __launch_bounds__(256) void gemm_mfma_k(
        const float* __restrict__ X, const unsigned short* __restrict__ Bhi,
        const unsigned short* __restrict__ Blo, float* __restrict__ Y,
        int n, int NO) {
    int wave = threadIdx.x >> 6;
    int lane = threadIdx.x & 63;
    int rowbase = (blockIdx.x * 4 + wave) * 32;
    if (rowbase >= n) return;
    int r0 = lane & 15, kg = lane >> 4;

    f32x4 acc[2][NC];
#pragma unroll
    for (int rt = 0; rt < 2; ++rt)
#pragma unroll
        for (int c = 0; c < NC; ++c) acc[rt][c] = f32x4{0.f, 0.f, 0.f, 0.f};

    for (int t = 0; t < 4; ++t) {
        union U { unsigned short u[8]; bf16x8 v; };
        U ah[2], al[2];
#pragma unroll
        for (int rt = 0; rt < 2; ++rt) {
            int row = min(rowbase + rt * 16 + r0, n - 1);
            const float* xp = X + (size_t)row * 128 + t * 32 + kg * 8;
            float4 xa = *reinterpret_cast<const float4*>(xp);
            float4 xb = *reinterpret_cast<const float4*>(xp + 4);
            float f[8] = {xa.x, xa.y, xa.z, xa.w, xb.x, xb.y, xb.z, xb.w};
#pragma unroll
            for (int i = 0; i < 8; ++i) {
                unsigned short h = bf16_rne(f[i]);
                ah[rt].u[i] = h;
                al[rt].u[i] = bf16_rne(f[i] - bf16_to_f(h));
            }
        }
#pragma unroll
        for (int c = 0; c < NC; ++c) {
            size_t boff = (((size_t)t * NC + c) * 64 + lane) * 8;
            bf16x8 bh = *reinterpret_cast<const bf16x8*>(Bhi + boff);
            bf16x8 bl = *reinterpret_cast<const bf16x8*>(Blo + boff);
#pragma unroll
            for (int rt = 0; rt < 2; ++rt) {
                acc[rt][c] = __builtin_amdgcn_mfma_f32_16x16x32_bf16(ah[rt].v, bh, acc[rt][c], 0, 0, 0);
                acc[rt][c] = __builtin_amdgcn_mfma_f32_16x16x32_bf16(al[rt].v, bh, acc[rt][c], 0, 0, 0);
                acc[rt][c] = __builtin_amdgcn_mfma_f32_16x16x32_bf16(ah[rt].v, bl, acc[rt][c], 0, 0, 0);
            }
        }
    }

#pragma unroll
    for (int rt = 0; rt < 2; ++rt)
#pragma unroll
        for (int c = 0; c < NC; ++c)
#pragma unroll
            for (int r = 0; r < 4; ++r) {
                int row = rowbase + rt * 16 + kg * 4 + r;
                int col = c * 16 + r0;
                if (row < n && col < NO)
                    Y[(size_t)row * NO + col] = acc[rt][c][r];
            }
}

// ===== attention logits per node (float4) ===================================
__global__ void scores_k(const float* __restrict__ H, const float* __restrict__ asrc,
                         const float* __restrict__ adst, float* __restrict__ ssrc,
                         float* __restrict__ sdst, int n, int heads, int ch) {
    int idx = blockIdx.x * blockDim.x + threadIdx.x;
    if (idx >= n * heads) return;
    int node = idx / heads, h = idx % heads;
    const float4* hp = reinterpret_cast<const float4*>(H + (size_t)node * heads * ch + h * ch);
    const float4* as = reinterpret_cast<const float4*>(asrc + h * ch);
    const float4* ad = reinterpret_cast<const float4*>(adst + h * ch);
    float a = 0.f, b = 0.f;
    for (int c = 0; c < ch / 4; ++c) {
        float4 v = hp[c], s = as[c], d = ad[c];
        a += v.x * s.x + v.y * s.y + v.z * s.z + v.w * s.w;
        b += v.x * d.x + v.y * d.y + v.z * d.z + v.w * d.w;
    }
    ssrc[idx] = a;
    sdst[idx] = b;
}

// ===== CSR build ============================================================
__global__ void hist_k(const int* __restrict__ ei, int E, int Etot, int* __restrict__ cnt) {
    int e = blockIdx.x * blockDim.x + threadIdx.x;
    if (e >= Etot) return;
    int d = (e < E) ? ei[E + e] : e - E;
    atomicAdd(&cnt[d], 1);
}

__global__ void scan1_k(const int* __restrict__ cnt, int* __restrict__ excl,
                        int* __restrict__ bsum, int n) {
    __shared__ int tmp[256];
    int i = blockIdx.x * 256 + threadIdx.x;
    int v = (i < n) ? cnt[i] : 0;
    tmp[threadIdx.x] = v;
    __syncthreads();
    for (int off = 1; off < 256; off <<= 1) {
        int t = (threadIdx.x >= off) ? tmp[threadIdx.x - off] : 0;
        __syncthreads();
        tmp[threadIdx.x] += t;
        __syncthreads();
    }
    if (i < n) excl[i] = tmp[threadIdx.x] - v;
    if (threadIdx.x == 255) bsum[blockIdx.x] = tmp[255];
}

__global__ void scan2_k(int* __restrict__ bsum, int nb) {
    __shared__ int tmp[512];
    int i = threadIdx.x;
    int v = (i < nb) ? bsum[i] : 0;
    tmp[i] = v;
    __syncthreads();
    for (int off = 1; off < 512; off <<= 1) {
        int t = (i >= off) ? tmp[i - off] : 0;
        __syncthreads();
        tmp[i] += t;
        __syncthreads();
    }
    if (i < nb) bsum[i] = tmp[i] - v;   // exclusive
}

__global__ void scan3_k(const int* __restrict__ excl, const int* __restrict__ bsum,
                        int* __restrict__ rowptr, int* __restrict__ cursor,
                        int n, int total) {
    int i = blockIdx.x * 256 + threadIdx.x;
    if (i < n) {
        int r = excl[i] + bsum[blockIdx.x];
        rowptr[i] = r;
        cursor[i] = r;
    }
    if (i == 0) rowptr[n] = total;
}

__global__ void scatter_k(const int* __restrict__ ei, int E, int Etot,
                          int* __restrict__ cursor, int* __restrict__ cols) {
    int e = blockIdx.x * blockDim.x + threadIdx.x;
    if (e >= Etot) return;
    int s, d;
    if (e < E) { s = ei[e]; d = ei[E + e]; } else { s = d = e - E; }
    int pos = atomicAdd(&cursor[d], 1);
    cols[pos] = s;
}

// ===== layers 0/1: fused per-node softmax + aggregation (F=128) =============
// one wave per node; 2 edges per inner iteration, float4 per lane
__global__ void gat_node128_k(const int* __restrict__ rp, const int* __restrict__ cols,
                              const float* __restrict__ H, const float* __restrict__ ssrc,
                              const float* __restrict__ sdst, const float* __restrict__ bias,
                              float* __restrict__ out, int n) {
    int d = blockIdx.x;
    if (d >= n) return;
    int lane = threadIdx.x;
    int beg = rp[d], deg = rp[d + 1] - beg;

    float4 sdv = *reinterpret_cast<const float4*>(sdst + (size_t)d * 4);
    float sd[4] = {sdv.x, sdv.y, sdv.z, sdv.w};

    // ---- phase 1: online max + denom ----
    float m[4], den[4];
#pragma unroll
    for (int h = 0; h < 4; ++h) { m[h] = -1e30f; den[h] = 0.f; }
    for (int i = lane; i < deg; i += 64) {
        int s = cols[beg + i];
        float4 t = *reinterpret_cast<const float4*>(ssrc + (size_t)s * 4);
        float sv[4] = {t.x, t.y, t.z, t.w};
#pragma unroll
        for (int h = 0; h < 4; ++h) {
            float v = sv[h] + sd[h];
            v = (v >= 0.f) ? v : NEG_SLOPE * v;
            float nm = fmaxf(m[h], v);
            den[h] = den[h] * __expf(m[h] - nm) + __expf(v - nm);
            m[h] = nm;
        }
    }
#pragma unroll
    for (int h = 0; h < 4; ++h) {
        for (int off = 32; off > 0; off >>= 1) {
            float om = __shfl_xor(m[h], off, 64);
            float od = __shfl_xor(den[h], off, 64);
            float nm = fmaxf(m[h], om);
            den[h] = den[h] * __expf(m[h] - nm) + od * __expf(om - nm);
            m[h] = nm;
        }
        den[h] = 1.f / (den[h] + 1e-16f);
    }

    // ---- phase 2: 2 edges/iter, float4 channels ----
    __shared__ float alpha_s[64 * 4];
    __shared__ int   src_s[64];
    int half = lane >> 5;
    int l32  = lane & 31;
    int head = l32 >> 3;
    float4 acc = {0.f, 0.f, 0.f, 0.f};

    for (int cbase = 0; cbase < deg; cbase += 64) {
        int cnt  = min(64, deg - cbase);
        int cntp = (cnt + 1) & ~1;
        __syncthreads();
        if (lane < cnt) {
            int s = cols[beg + cbase + lane];
            src_s[lane] = s;
            float4 t = *reinterpret_cast<const float4*>(ssrc + (size_t)s * 4);
            float sv[4] = {t.x, t.y, t.z, t.w};
#pragma unroll
            for (int h = 0; h < 4; ++h) {
                float v = sv[h] + sd[h];
                v = (v >= 0.f) ? v : NEG_SLOPE * v;
                alpha_s[lane * 4 + h] = __expf(v - m[h]) * den[h];
            }
        } else if (lane < cntp) {
            src_s[lane] = d;
#pragma unroll
            for (int h = 0; h < 4; ++h) alpha_s[lane * 4 + h] = 0.f;
        }
        __syncthreads();
#pragma unroll 2
        for (int p = 0; p < cntp; p += 2) {
            int e = p + half;
            int s = src_s[e];
            float a = alpha_s[e * 4 + head];
            float4 v = *reinterpret_cast<const float4*>(H + (size_t)s * 128 + l32 * 4);
            acc.x += a * v.x; acc.y += a * v.y; acc.z += a * v.z; acc.w += a * v.w;
        }
    }

    // ---- combine halves + bias + ELU + store ----
    acc.x += __shfl_xor(acc.x, 32, 64);
    acc.y += __shfl_xor(acc.y, 32, 64);
    acc.z += __shfl_xor(acc.z, 32, 64);
    acc.w += __shfl_xor(acc.w, 32, 64);
    if (half == 0) {
        float4 b = *reinterpret_cast<const float4*>(bias + l32 * 4);
        float4 v;
        v.x = acc.x + b.x; v.y = acc.y + b.y; v.z = acc.z + b.z; v.w = acc.w + b.w;
        v.x = (v.x > 0.f) ? v.x : expm1f(v.x);
        v.y = (v.y > 0.f) ? v.y : expm1f(v.y);
        v.z = (v.z > 0.f) ? v.z : expm1f(v.z);
        v.w = (v.w > 0.f) ? v.w : expm1f(v.w);
        *reinterpret_cast<float4*>(out + (size_t)d * 128 + l32 * 4) = v;
    }
}

// ===== layer 2: fused softmax + aggregation + bias + log_softmax (F=40) =====
// one wave per node; 6 edges per inner iteration (10 float4 lanes each)
__global__ void gat_node40_k(const int* __restrict__ rp, const int* __restrict__ cols,
                             const float* __restrict__ H, const float* __restrict__ ssrc,
                             const float* __restrict__ sdst, const float* __restrict__ b2,
                             float* __restrict__ out, int n) {
    int d = blockIdx.x;
    if (d >= n) return;
    int lane = threadIdx.x;
    int beg = rp[d], deg = rp[d + 1] - beg;
    float sd = sdst[d];

    // ---- phase 1: online max + denom ----
    float m = -1e30f, den = 0.f;
    for (int i = lane; i < deg; i += 64) {
        int s = cols[beg + i];
        float v = ssrc[s] + sd;
        v = (v >= 0.f) ? v : NEG_SLOPE * v;
        float nm = fmaxf(m, v);
        den = den * __expf(m - nm) + __expf(v - nm);
        m = nm;
    }
    for (int off = 32; off > 0; off >>= 1) {
        float om = __shfl_xor(m, off, 64);
        float od = __shfl_xor(den, off, 64);
        float nm = fmaxf(m, om);
        den = den * __expf(m - nm) + od * __expf(om - nm);
        m = nm;
    }
    float rden = 1.f / (den + 1e-16f);

    // ---- phase 2: 6 edges/iter ----
    __shared__ float alpha_s[66];
    __shared__ int   src_s[66];
    if (lane < 6) { alpha_s[60 + lane] = 0.f; src_s[60 + lane] = d; }

    int slot = lane / 10;     // 0..5 active, 6 = idle lanes 60-63
    int g    = lane % 10;     // float4 channel group
    float4 acc = {0.f, 0.f, 0.f, 0.f};

    for (int cbase = 0; cbase < deg; cbase += 60) {
        int cnt  = min(60, deg - cbase);
        int cnt6 = ((cnt + 5) / 6) * 6;
        __syncthreads();
        if (lane < cnt) {
            int s = cols[beg + cbase + lane];
            src_s[lane] = s;
            float v = ssrc[s] + sd;
            v = (v >= 0.f) ? v : NEG_SLOPE * v;
            alpha_s[lane] = __expf(v - m) * rden;
        } else if (lane < cnt6) {
            src_s[lane] = d;
            alpha_s[lane] = 0.f;
        }
        __syncthreads();
        for (int p = 0; p < cnt6; p += 6) {
            int e = (slot < 6) ? (p + slot) : 60;
            int s = src_s[e];
            float a = alpha_s[e];
            float4 v = *reinterpret_cast<const float4*>(H + (size_t)s * 40 + g * 4);
            acc.x += a * v.x; acc.y += a * v.y; acc.z += a * v.z; acc.w += a * v.w;
        }
    }

    // ---- combine slots: {0..5} -> slot 0 (lanes 0-9) ----
    float4 t;
    t.x = __shfl(acc.x, lane + 30, 64);
    t.y = __shfl(acc.y, lane + 30, 64);
    t.z = __shfl(acc.z, lane + 30, 64);
    t.w = __shfl(acc.w, lane + 30, 64);
    if (lane < 30) { acc.x += t.x; acc.y += t.y; acc.z += t.z; acc.w += t.w; }
    float4 t1, t2;
    t1.x = __shfl(acc.x, lane + 10, 64);
    t1.y = __shfl(acc.y, lane + 10, 64);
    t1.z = __shfl(acc.z, lane + 10, 64);
    t1.w = __shfl(acc.w, lane + 10, 64);
    t2.x = __shfl(acc.x, lane + 20, 64);
    t2.y = __shfl(acc.y, lane + 20, 64);
    t2.z = __shfl(acc.z, lane + 20, 64);
    t2.w = __shfl(acc.w, lane + 20, 64);
    if (lane < 10) {
        acc.x += t1.x + t2.x; acc.y += t1.y + t2.y;
        acc.z += t1.z + t2.z; acc.w += t1.w + t2.w;
    }

    // ---- bias + log_softmax across lanes 0-9 (40 logits) ----
    float4 v4 = {0.f, 0.f, 0.f, 0.f};
    if (lane < 10) {
        float4 b = *reinterpret_cast<const float4*>(b2 + lane * 4);
        v4.x = acc.x + b.x; v4.y = acc.y + b.y;
        v4.z = acc.z + b.z; v4.w = acc.w + b.w;
    }
    float mm = (lane < 10) ? fmaxf(fmaxf(v4.x, v4.y), fmaxf(v4.z, v4.w)) : -1e30f;
    for (int off = 8; off > 0; off >>= 1) mm = fmaxf(mm, __shfl_xor(mm, off, 16));
    float ss = 0.f;
    if (lane < 10)
        ss = __expf(v4.x - mm) + __expf(v4.y - mm) + __expf(v4.z - mm) + __expf(v4.w - mm);
    for (int off = 8; off > 0; off >>= 1) ss += __shfl_xor(ss, off, 16);
    float lse = mm + logf(ss);
    if (lane < 10) {
        float4 r;
        r.x = v4.x - lse; r.y = v4.y - lse; r.z = v4.z - lse; r.w = v4.w - lse;
        *reinterpret_cast<float4*>(out + (size_t)d * 40 + lane * 4) = r;
    }
}

static inline dim3 g1(long t) { return dim3((unsigned)((t + 255) / 256)); }

extern "C" void kernel_launch(void* const* d_in, const int* in_sizes, int n_in,
                              void* d_out, int out_size, void* d_ws, size_t ws_size,
                              hipStream_t stream) {
    const float* x      = (const float*)d_in[0];
    const int*   ei     = (const int*)d_in[1];
    const float* W0     = (const float*)d_in[2];
    const float* a_src0 = (const float*)d_in[3];
    const float* a_dst0 = (const float*)d_in[4];
    const float* b0     = (const float*)d_in[5];
    const float* W1     = (const float*)d_in[6];
    const float* a_src1 = (const float*)d_in[7];
    const float* a_dst1 = (const float*)d_in[8];
    const float* b1     = (const float*)d_in[9];
    const float* W2     = (const float*)d_in[10];
    const float* a_src2 = (const float*)d_in[11];
    const float* a_dst2 = (const float*)d_in[12];
    const float* b2     = (const float*)d_in[13];

    const int N    = in_sizes[0] / FIN;
    const int E    = in_sizes[1] / 2;
    const int Etot = E + N;

    float* ws = (float*)d_ws;
    size_t o = 0;
    float* hA   = ws + o; o += (size_t)N * FIN;
    float* hB   = ws + o; o += (size_t)N * FIN;
    float* ssrc = ws + o; o += (size_t)N * HEADS;
    float* sdst = ws + o; o += (size_t)N * HEADS;
    int* cnt    = (int*)(ws + o); o += N;
    int* excl   = (int*)(ws + o); o += N;
    int* bsum   = (int*)(ws + o); o += 512;
    int* rowptr = (int*)(ws + o); o += N + 1;
    int* cursor = (int*)(ws + o); o += N;
    int* cols   = (int*)(ws + o); o += Etot;
    unsigned short* Bhi0 = (unsigned short*)(ws + o); o += 4 * 8 * 64 * 8 / 2;
    unsigned short* Blo0 = (unsigned short*)(ws + o); o += 4 * 8 * 64 * 8 / 2;
    unsigned short* Bhi1 = (unsigned short*)(ws + o); o += 4 * 8 * 64 * 8 / 2;
    unsigned short* Blo1 = (unsigned short*)(ws + o); o += 4 * 8 * 64 * 8 / 2;
    unsigned short* Bhi2 = (unsigned short*)(ws + o); o += 4 * 3 * 64 * 8 / 2;
    unsigned short* Blo2 = (unsigned short*)(ws + o); o += 4 * 3 * 64 * 8 / 2;

    const int nScanBlocks = (N + 255) / 256;
    const int gemmBlocks  = (N + 127) / 128;

    // ---------------- CSR by destination + weight packing (shared) ----------
    hipMemsetAsync(cnt, 0, (size_t)N * 4, stream);
    hist_k<<<g1(Etot), 256, 0, stream>>>(ei, E, Etot, cnt);
    packW_k<8><<<g1(4 * 8 * 64 * 8), 256, 0, stream>>>(W0, Bhi0, Blo0, 128);
    packW_k<8><<<g1(4 * 8 * 64 * 8), 256, 0, stream>>>(W1, Bhi1, Blo1, 128);
    packW_k<3><<<g1(4 * 3 * 64 * 8), 256, 0, stream>>>(W2, Bhi2, Blo2, NCLS);
    scan1_k<<<nScanBlocks, 256, 0, stream>>>(cnt, excl, bsum, N);
    scan2_k<<<1, 512, 0, stream>>>(bsum, nScanBlocks);
    scan3_k<<<nScanBlocks, 256, 0, stream>>>(excl, bsum, rowptr, cursor, N, Etot);
    scatter_k<<<g1(Etot), 256, 0, stream>>>(ei, E, Etot, cursor, cols);

    // ---------------- Layer 0 ----------------------------------------------
    gemm_mfma_k<8><<<gemmBlocks, 256, 0, stream>>>(x, Bhi0, Blo0, hA, N, 128);
    scores_k<<<g1((long)N * HEADS), 256, 0, stream>>>(hA, a_src0, a_dst0, ssrc, sdst, N, HEADS, HID);
    gat_node128_k<<<N, 64, 0, stream>>>(rowptr, cols, hA, ssrc, sdst, b0, hB, N);

    // ---------------- Layer 1 ----------------------------------------------
    gemm_mfma_k<8><<<gemmBlocks, 256, 0, stream>>>(hB, Bhi1, Blo1, hA, N, 128);
    scores_k<<<g1((long)N * HEADS), 256, 0, stream>>>(hA, a_src1, a_dst1, ssrc, sdst, N, HEADS, HID);
    gat_node128_k<<<N, 64, 0, stream>>>(rowptr, cols, hA, ssrc, sdst, b1, hB, N);

    // ---------------- Layer 2 (fused bias + log_softmax) --------------------
    gemm_mfma_k<3><<<gemmBlocks, 256, 0, stream>>>(hB, Bhi2, Blo2, hA, N, NCLS);
    scores_k<<<g1((long)N * 1), 256, 0, stream>>>(hA, a_src2, a_dst2, ssrc, sdst, N, 1, NCLS);
    gat_node40_k<<<N, 64, 0, stream>>>(rowptr, cols, hA, ssrc, sdst, b2, (float*)d_out, N);
}